// Round 5
// baseline (121.150 us; speedup 1.0000x reference)
//
#include <hip/hip_runtime.h>
#include <math.h>

// Problem constants
#define NBATCH 4
#define NCLS   19
#define HWDIM  512
#define HW     (512 * 512)      // 262144
#define PH     171              // pooled H=W
#define PP2    (171 * 171)      // 29241
#define NHW    169              // PH - radius + 1
#define MM     (169 * 169)      // 28561
#define ZB     6                // stage2 row-bands
#define HMAX   31               // max band rows + 2 halo

// ---------------------------------------------------------------------------
// Stage 1 (round-3 proven version): fused softmax + one-hot + 3x3/stride-3
// avg-pool. One block per (n, pooled-row ph); thread = input column.
// ---------------------------------------------------------------------------
__global__ __launch_bounds__(512) void stage1_pool(
    const float* __restrict__ cls, const int* __restrict__ label,
    float* __restrict__ P, float* __restrict__ L) {
  int n  = blockIdx.x / PH;
  int ph = blockIdx.x - n * PH;
  int col = threadIdx.x;  // input column 0..511

  float accP[NCLS], accL[NCLS];
#pragma unroll
  for (int c = 0; c < NCLS; ++c) { accP[c] = 0.f; accL[c] = 0.f; }

#pragma unroll
  for (int i = 0; i < 3; ++i) {
    int r = 3 * ph - 1 + i;
    if (r < 0 || r >= HWDIM) continue;
    int lb = label[((size_t)n * HWDIM + r) * HWDIM + col];
    const float* base = cls + (size_t)n * NCLS * HW + (size_t)r * HWDIM + col;
    float v[NCLS];
    float mx = -INFINITY;
#pragma unroll
    for (int c = 0; c < NCLS; ++c) {
      v[c] = base[(size_t)c * HW];
      mx = fmaxf(mx, v[c]);
    }
    float se = 0.f;
#pragma unroll
    for (int c = 0; c < NCLS; ++c) {
      v[c] = expf(v[c] - mx);
      se += v[c];
    }
    // valid = (lb>=0 && lb<19); invalid zeroes BOTH probs and onehot.
    if (lb >= 0 && lb < NCLS) {
      float inv = 1.f / se;
#pragma unroll
      for (int c = 0; c < NCLS; ++c) {
        accP[c] += v[c] * inv;
        accL[c] += (lb == c) ? 1.f : 0.f;  // compile-time index
      }
    }
  }

  // x-pool: xb[cc][1+q] = column q accumulator; xb[cc][0] = left pad (zero).
  __shared__ float xbP[4][516];
  __shared__ float xbL[4][516];
  const float inv9 = 1.f / 9.f;
#pragma unroll
  for (int c0 = 0; c0 < NCLS; c0 += 4) {
    int nc_round = (NCLS - c0) < 4 ? (NCLS - c0) : 4;
#pragma unroll
    for (int cc = 0; cc < 4; ++cc) {
      if (cc < nc_round) {
        xbP[cc][1 + col] = accP[(c0 + cc) < NCLS ? (c0 + cc) : 0];
        xbL[cc][1 + col] = accL[(c0 + cc) < NCLS ? (c0 + cc) : 0];
        if (col == 0) { xbP[cc][0] = 0.f; xbL[cc][0] = 0.f; }
      }
    }
    __syncthreads();
    if (col < PH) {
      int pw = col;
#pragma unroll
      for (int cc = 0; cc < 4; ++cc) {
        if (cc < nc_round) {
          int c = c0 + cc;
          float sP = xbP[cc][3 * pw] + xbP[cc][3 * pw + 1] + xbP[cc][3 * pw + 2];
          float sL = xbL[cc][3 * pw] + xbL[cc][3 * pw + 1] + xbL[cc][3 * pw + 2];
          size_t o = ((size_t)(n * NCLS + c)) * PP2 + (size_t)ph * PH + pw;
          P[o] = sP * inv9;
          L[o] = sL * inv9;
        }
      }
    }
    __syncthreads();
  }
}

// ---------------------------------------------------------------------------
// Stage 2: per (nc, part, band) moment accumulation. The band's pooled rows
// (contiguous in global) are staged into LDS with coalesced reads; the
// sliding-window moment loop reads LDS (6 cy) instead of global (~200 cy).
// Moment layout per (z,nc) record, stride 192 floats:
//   [0..8] sum la | [9..17] sum pr | [18..62] la*la ut45 | [63..107] pr*pr ut45
//   [108..188] pr[d]*la[e] (81) | [190..191] (double) logdet (z=0 record only)
// ---------------------------------------------------------------------------
template <int PART>
__device__ __forceinline__ void mom_body(
    int bw, const float* sP, const float* sL,
    float* __restrict__ covp, int rec, float* red) {
  constexpr int NA  = (PART == 0) ? 63 : (PART == 1 ? 45 : 81);
  constexpr int OFF = (PART == 0) ? 0  : (PART == 1 ? 63 : 108);

  float acc[NA];
#pragma unroll
  for (int k = 0; k < NA; ++k) acc[k] = 0.f;

  int task = threadIdx.x;  // 507 tasks: (ysub, xx); rows relative to band
  if (task < 3 * NHW) {
    int ysub = task / NHW;
    int xx   = task - ysub * NHW;
    int y0 = (bw * ysub) / 3;
    int y1 = (bw * (ysub + 1)) / 3;

    float wp[9], wl[9];
    // prime rows y0, y0+1 -> slots 0..5
#pragma unroll
    for (int dy = 0; dy < 2; ++dy) {
#pragma unroll
      for (int dx = 0; dx < 3; ++dx) {
        wp[dy * 3 + dx] = sP[(y0 + dy) * PH + xx + dx];
        if (PART != 1) wl[dy * 3 + dx] = sL[(y0 + dy) * PH + xx + dx];
      }
    }
    for (int y = y0; y < y1; ++y) {
#pragma unroll
      for (int dx = 0; dx < 3; ++dx) {
        wp[6 + dx] = sP[(y + 2) * PH + xx + dx];
        if (PART != 1) wl[6 + dx] = sL[(y + 2) * PH + xx + dx];
      }
      if (PART == 0) {
#pragma unroll
        for (int d = 0; d < 9; ++d) {
          acc[d]     += wl[d];
          acc[9 + d] += wp[d];
        }
        int k = 18;
#pragma unroll
        for (int d = 0; d < 9; ++d)
#pragma unroll
          for (int e = d; e < 9; ++e) { acc[k] += wl[d] * wl[e]; ++k; }
      } else if (PART == 1) {
        int k = 0;
#pragma unroll
        for (int d = 0; d < 9; ++d)
#pragma unroll
          for (int e = d; e < 9; ++e) { acc[k] += wp[d] * wp[e]; ++k; }
      } else {
#pragma unroll
        for (int d = 0; d < 9; ++d)
#pragma unroll
          for (int e = 0; e < 9; ++e) acc[d * 9 + e] += wp[d] * wl[e];
      }
      // shift window up one row (static indices)
#pragma unroll
      for (int s = 0; s < 6; ++s) {
        wp[s] = wp[s + 3];
        if (PART != 1) wl[s] = wl[s + 3];
      }
    }
  }

  int lane = threadIdx.x & 63;
  int wid  = threadIdx.x >> 6;  // 8 waves
#pragma unroll
  for (int k = 0; k < NA; ++k) {
    float v = acc[k];
#pragma unroll
    for (int o = 32; o > 0; o >>= 1) v += __shfl_down(v, o, 64);
    if (lane == 0) red[wid * NA + k] = v;
  }
  __syncthreads();
  if (threadIdx.x < NA) {
    float s = 0.f;
#pragma unroll
    for (int w = 0; w < 8; ++w) s += red[w * NA + threadIdx.x];
    covp[(size_t)rec * 192 + OFF + threadIdx.x] = s;
  }
}

__global__ __launch_bounds__(512) void stage2_mom(
    const float* __restrict__ P, const float* __restrict__ L,
    float* __restrict__ covp) {
  __shared__ float sP[HMAX * PH];
  __shared__ float sL[HMAX * PH];
  __shared__ float red[8 * 81];
  int nc = blockIdx.x;
  int part = blockIdx.y;
  int z  = blockIdx.z;
  int w0 = (NHW * z) / ZB;
  int w1 = (NHW * (z + 1)) / ZB;
  int bw = w1 - w0;           // band window-rows (28 or 29)
  int tot = (bw + 2) * PH;    // pooled rows to stage (contiguous in global)

  const float* Pp = P + (size_t)nc * PP2 + (size_t)w0 * PH;
  const float* Lp = L + (size_t)nc * PP2 + (size_t)w0 * PH;
  for (int i = threadIdx.x; i < tot; i += 512) {
    sP[i] = Pp[i];
    if (part != 1) sL[i] = Lp[i];
  }
  __syncthreads();

  int rec = z * (NBATCH * NCLS) + nc;
  if (part == 0)      mom_body<0>(bw, sP, sL, covp, rec, red);
  else if (part == 1) mom_body<1>(bw, sP, sL, covp, rec, red);
  else                mom_body<2>(bw, sP, sL, covp, rec, red);
}

// ---------------------------------------------------------------------------
// Stage 3: one 64-thread block per (n,c). Sums the ZB partials, builds
// covariances in fp64 in LDS, Cholesky(la_cov+1e-5 I), triangular solve,
// Schur complement + 1e-6 I, Cholesky logdet. Result -> covp[nc*192+190..191].
// ---------------------------------------------------------------------------
__global__ __launch_bounds__(64) void stage3_rmi(float* __restrict__ covp) {
  int nc  = blockIdx.x;
  int tid = threadIdx.x;
  __shared__ double lc[81], pc[81], plc[81], mla[9], mpr[9];
  const double Minv = 1.0 / (double)MM;

  // LDM(k): sum the ZB band partials
#define LDM(k) ( (double)covp[(size_t)(0 * NBATCH * NCLS + nc) * 192 + (k)] \
               + (double)covp[(size_t)(1 * NBATCH * NCLS + nc) * 192 + (k)] \
               + (double)covp[(size_t)(2 * NBATCH * NCLS + nc) * 192 + (k)] \
               + (double)covp[(size_t)(3 * NBATCH * NCLS + nc) * 192 + (k)] \
               + (double)covp[(size_t)(4 * NBATCH * NCLS + nc) * 192 + (k)] \
               + (double)covp[(size_t)(5 * NBATCH * NCLS + nc) * 192 + (k)] )

  if (tid < 9)       mla[tid]     = LDM(tid) * Minv;
  else if (tid < 18) mpr[tid - 9] = LDM(tid) * Minv;
  __syncthreads();

  for (int e = tid; e < 81; e += 64) {
    int r = e / 9, c = e - 9 * (e / 9);
    int lo = r < c ? r : c, hi = r < c ? c : r;
    int k = lo * 9 - lo * (lo - 1) / 2 + (hi - lo);
    double a = LDM(18 + k) * Minv - mla[r] * mla[c];
    if (r == c) a += 1e-5;
    lc[e] = a;
    pc[e] = LDM(63 + k) * Minv - mpr[r] * mpr[c];
    plc[e] = LDM(108 + e) * Minv - mpr[r] * mla[c];
  }
  __syncthreads();

  // Cholesky of lc (lower), column-by-column
  for (int j = 0; j < 9; ++j) {
    if (tid == 0) lc[j * 9 + j] = sqrt(lc[j * 9 + j]);
    __syncthreads();
    if (tid > j && tid < 9) lc[tid * 9 + j] /= lc[j * 9 + j];
    __syncthreads();
    if (tid > j && tid < 9) {
      double lij = lc[tid * 9 + j];
      for (int k = j + 1; k <= tid; ++k) lc[tid * 9 + k] -= lij * lc[k * 9 + j];
    }
    __syncthreads();
  }

  // Solve W * L1^T = plc (row d per lane), in place
  if (tid < 9) {
    int d = tid;
    for (int j = 0; j < 9; ++j) {
      double t = plc[d * 9 + j];
      for (int k = 0; k < j; ++k) t -= plc[d * 9 + k] * lc[j * 9 + k];
      plc[d * 9 + j] = t / lc[j * 9 + j];
    }
  }
  __syncthreads();

  // A = pc - W W^T + 1e-6 I (in place in pc)
  for (int e = tid; e < 81; e += 64) {
    int r = e / 9, c = e - 9 * (e / 9);
    double a = pc[e];
    for (int f = 0; f < 9; ++f) a -= plc[r * 9 + f] * plc[c * 9 + f];
    if (r == c) a += 1e-6;
    pc[e] = a;
  }
  __syncthreads();

  // Cholesky of pc
  for (int j = 0; j < 9; ++j) {
    if (tid == 0) pc[j * 9 + j] = sqrt(pc[j * 9 + j]);
    __syncthreads();
    if (tid > j && tid < 9) pc[tid * 9 + j] /= pc[j * 9 + j];
    __syncthreads();
    if (tid > j && tid < 9) {
      double lij = pc[tid * 9 + j];
      for (int k = j + 1; k <= tid; ++k) pc[tid * 9 + k] -= lij * pc[k * 9 + j];
    }
    __syncthreads();
  }

  if (tid == 0) {
    double sl = 0.0;
    for (int j = 0; j < 9; ++j) sl += log(pc[j * 9 + j] + 1e-8);
    *(double*)(covp + (size_t)nc * 192 + 190) = sl;  // rmi_{n,c}
  }
#undef LDM
}

// ---------------------------------------------------------------------------
// Stage 4: reduce 76 fp64 partials -> out[0] = sum / (N * NUM_CLASSES)
// ---------------------------------------------------------------------------
__global__ __launch_bounds__(64) void stage4_reduce(
    const float* __restrict__ covp, float* __restrict__ out) {
  int tid = threadIdx.x;
  double v = 0.0;
  if (tid < NBATCH * NCLS)
    v = *(const double*)(covp + (size_t)tid * 192 + 190);
  if (tid + 64 < NBATCH * NCLS)
    v += *(const double*)(covp + (size_t)(tid + 64) * 192 + 190);
#pragma unroll
  for (int o = 32; o > 0; o >>= 1) v += __shfl_down(v, o, 64);
  if (tid == 0) out[0] = (float)(v / (double)(NBATCH * NCLS));
}

// ---------------------------------------------------------------------------
extern "C" void kernel_launch(void* const* d_in, const int* in_sizes, int n_in,
                              void* d_out, int out_size, void* d_ws, size_t ws_size,
                              hipStream_t stream) {
  const float* cls  = (const float*)d_in[0];
  const int* label  = (const int*)d_in[1];
  float* out = (float*)d_out;

  float* P    = (float*)d_ws;                              // 76*29241 f32
  float* L    = P + (size_t)NBATCH * NCLS * PP2;           // 76*29241 f32
  float* covp = L + (size_t)NBATCH * NCLS * PP2;           // ZB*76*192 f32

  stage1_pool<<<NBATCH * PH, 512, 0, stream>>>(cls, label, P, L);
  dim3 g2(NBATCH * NCLS, 3, ZB);
  stage2_mom<<<g2, 512, 0, stream>>>(P, L, covp);
  stage3_rmi<<<NBATCH * NCLS, 64, 0, stream>>>(covp);
  stage4_reduce<<<1, 64, 0, stream>>>(covp, out);
}

// Round 6
// 76.562 us; speedup vs baseline: 1.5824x; 1.5824x over previous
//
#include <hip/hip_runtime.h>
#include <math.h>

// Problem constants
#define NBATCH 4
#define NCLS   19
#define HWDIM  512
#define HW     (512 * 512)      // 262144
#define PH     171              // pooled H=W
#define PHP    176              // padded row stride (16B-aligned rows)
#define PP2A   (171 * 176)      // 30096 floats per (n,c) plane
#define NHW    169              // PH - radius + 1
#define MM     (169 * 169)      // 28561
#define NBAND  11               // stage2 y-bands per strip
#define NSTRIP 43               // ceil(169/4) strips of 4 positions

typedef float f4 __attribute__((ext_vector_type(4)));
typedef float f2 __attribute__((ext_vector_type(2)));

// ---------------------------------------------------------------------------
// Stage 1 (round-3 proven structure): fused softmax + one-hot + 3x3/stride-3
// avg-pool. One block per (n, pooled-row ph); thread = input column.
// Output row stride PHP=176; pad cols 171..175 zero-filled.
// ---------------------------------------------------------------------------
__global__ __launch_bounds__(512) void stage1_pool(
    const float* __restrict__ cls, const int* __restrict__ label,
    float* __restrict__ P, float* __restrict__ L) {
  int n  = blockIdx.x / PH;
  int ph = blockIdx.x - n * PH;
  int col = threadIdx.x;  // input column 0..511

  float accP[NCLS], accL[NCLS];
#pragma unroll
  for (int c = 0; c < NCLS; ++c) { accP[c] = 0.f; accL[c] = 0.f; }

#pragma unroll
  for (int i = 0; i < 3; ++i) {
    int r = 3 * ph - 1 + i;
    if (r < 0 || r >= HWDIM) continue;
    int lb = label[((size_t)n * HWDIM + r) * HWDIM + col];
    const float* base = cls + (size_t)n * NCLS * HW + (size_t)r * HWDIM + col;
    float v[NCLS];
    float mx = -INFINITY;
#pragma unroll
    for (int c = 0; c < NCLS; ++c) {
      v[c] = base[(size_t)c * HW];
      mx = fmaxf(mx, v[c]);
    }
    float se = 0.f;
#pragma unroll
    for (int c = 0; c < NCLS; ++c) {
      v[c] = expf(v[c] - mx);
      se += v[c];
    }
    // valid = (lb>=0 && lb<19); invalid zeroes BOTH probs and onehot.
    if (lb >= 0 && lb < NCLS) {
      float inv = 1.f / se;
#pragma unroll
      for (int c = 0; c < NCLS; ++c) {
        accP[c] += v[c] * inv;
        accL[c] += (lb == c) ? 1.f : 0.f;  // compile-time index
      }
    }
  }

  // x-pool: xb[cc][1+q] = column q accumulator; xb[cc][0] = left pad (zero).
  __shared__ float xbP[4][516];
  __shared__ float xbL[4][516];
  const float inv9 = 1.f / 9.f;
#pragma unroll
  for (int c0 = 0; c0 < NCLS; c0 += 4) {
    int nc_round = (NCLS - c0) < 4 ? (NCLS - c0) : 4;
#pragma unroll
    for (int cc = 0; cc < 4; ++cc) {
      if (cc < nc_round) {
        xbP[cc][1 + col] = accP[(c0 + cc) < NCLS ? (c0 + cc) : 0];
        xbL[cc][1 + col] = accL[(c0 + cc) < NCLS ? (c0 + cc) : 0];
        if (col == 0) { xbP[cc][0] = 0.f; xbL[cc][0] = 0.f; }
      }
    }
    __syncthreads();
    if (col < PH) {
      int pw = col;
#pragma unroll
      for (int cc = 0; cc < 4; ++cc) {
        if (cc < nc_round) {
          int c = c0 + cc;
          float sP = xbP[cc][3 * pw] + xbP[cc][3 * pw + 1] + xbP[cc][3 * pw + 2];
          float sL = xbL[cc][3 * pw] + xbL[cc][3 * pw + 1] + xbL[cc][3 * pw + 2];
          size_t o = ((size_t)(n * NCLS + c)) * PP2A + (size_t)ph * PHP + pw;
          P[o] = sP * inv9;
          L[o] = sL * inv9;
        }
      }
    } else if (col < PHP) {
      // zero the pad columns so stage2 strip loads see zeros
#pragma unroll
      for (int cc = 0; cc < 4; ++cc) {
        if (cc < nc_round) {
          int c = c0 + cc;
          size_t o = ((size_t)(n * NCLS + c)) * PP2A + (size_t)ph * PHP + col;
          P[o] = 0.f;
          L[o] = 0.f;
        }
      }
    }
    __syncthreads();
  }
}

// ---------------------------------------------------------------------------
// Stage 2: per (n,c) raw-moment accumulation over M=169^2 window positions.
// Strip processing: thread owns 4 positions (cols x0..x0+3); per row-step it
// loads ONE f4 + ONE f2 per plane (6 floats, 16B/8B aligned via PHP=176) and
// does 4xNA FMAs -- load latency hides under the FMA block (prefetch-1-row).
// Grid (76, 3); 43 strips x 11 y-bands = 473 active threads of 512.
// Moment layout per nc record, stride 192 floats:
//   [0..8] sum la | [9..17] sum pr | [18..62] la*la ut45 | [63..107] pr*pr ut45
//   [108..188] pr[d]*la[e] (81) | [190..191] (double) logdet from stage3
// ---------------------------------------------------------------------------
template <int PART>
__device__ __forceinline__ void mom_body(
    const float* __restrict__ Pp, const float* __restrict__ Lp,
    float* __restrict__ covp, int nc, float* red) {
  constexpr int NA  = (PART == 0) ? 63 : (PART == 1 ? 45 : 81);
  constexpr int OFF = (PART == 0) ? 0  : (PART == 1 ? 63 : 108);

  float acc[NA];
#pragma unroll
  for (int k = 0; k < NA; ++k) acc[k] = 0.f;

  int tid = threadIdx.x;
  if (tid < NSTRIP * NBAND) {
    int b  = tid / NSTRIP;
    int s  = tid - b * NSTRIP;
    int x0 = 4 * s;                    // 0..168; cols x0..x0+5 <= 173 < 176
    int y0 = (NHW * b) / NBAND;
    int y1 = (NHW * (b + 1)) / NBAND;  // rows y0..y1-1; reads rows up to y1+1

    float wp[18], wl[18];              // 3 rows x 6 cols per plane
    // prime rows y0..y0+2
#pragma unroll
    for (int r = 0; r < 3; ++r) {
      const float* rp = Pp + (y0 + r) * PHP + x0;
      *(f4*)&wp[r * 6]     = *(const f4*)rp;
      *(f2*)&wp[r * 6 + 4] = *(const f2*)(rp + 4);
      if (PART != 1) {
        const float* rl = Lp + (y0 + r) * PHP + x0;
        *(f4*)&wl[r * 6]     = *(const f4*)rl;
        *(f2*)&wl[r * 6 + 4] = *(const f2*)(rl + 4);
      }
    }

    for (int y = y0; y < y1; ++y) {
      // prefetch row y+3 (clamped; last-iter value unused garbage is fine)
      int yn = (y + 3 <= PH - 1) ? (y + 3) : (PH - 1);
      const float* rp = Pp + yn * PHP + x0;
      f4 tp4 = *(const f4*)rp;
      f2 tp2 = *(const f2*)(rp + 4);
      f4 tl4; f2 tl2;
      if (PART != 1) {
        const float* rl = Lp + yn * PHP + x0;
        tl4 = *(const f4*)rl;
        tl2 = *(const f2*)(rl + 4);
      }
      // FMA block: 4 positions on window rows y..y+2
#pragma unroll
      for (int p = 0; p < 4; ++p) {
        if (x0 + p < NHW) {  // exec-mask invalid tail positions (strip 42)
          if (PART == 0) {
#pragma unroll
            for (int dy = 0; dy < 3; ++dy)
#pragma unroll
              for (int dx = 0; dx < 3; ++dx) {
                int d = dy * 3 + dx;
                acc[d]     += wl[dy * 6 + p + dx];
                acc[9 + d] += wp[dy * 6 + p + dx];
              }
            int k = 18;
#pragma unroll
            for (int d = 0; d < 9; ++d)
#pragma unroll
              for (int e = d; e < 9; ++e) {
                acc[k] += wl[(d / 3) * 6 + p + (d % 3)] *
                          wl[(e / 3) * 6 + p + (e % 3)];
                ++k;
              }
          } else if (PART == 1) {
            int k = 0;
#pragma unroll
            for (int d = 0; d < 9; ++d)
#pragma unroll
              for (int e = d; e < 9; ++e) {
                acc[k] += wp[(d / 3) * 6 + p + (d % 3)] *
                          wp[(e / 3) * 6 + p + (e % 3)];
                ++k;
              }
          } else {
#pragma unroll
            for (int d = 0; d < 9; ++d)
#pragma unroll
              for (int e = 0; e < 9; ++e)
                acc[d * 9 + e] += wp[(d / 3) * 6 + p + (d % 3)] *
                                  wl[(e / 3) * 6 + p + (e % 3)];
          }
        }
      }
      // shift window up one row; commit prefetch (all static indices)
#pragma unroll
      for (int t = 0; t < 12; ++t) {
        wp[t] = wp[t + 6];
        if (PART != 1) wl[t] = wl[t + 6];
      }
      *(f4*)&wp[12] = tp4;
      *(f2*)&wp[16] = tp2;
      if (PART != 1) {
        *(f4*)&wl[12] = tl4;
        *(f2*)&wl[16] = tl2;
      }
    }
  }

  // wave shuffle-reduce (64-lane) then cross-wave via LDS
  int lane = threadIdx.x & 63;
  int wid  = threadIdx.x >> 6;  // 8 waves
#pragma unroll
  for (int k = 0; k < NA; ++k) {
    float v = acc[k];
#pragma unroll
    for (int o = 32; o > 0; o >>= 1) v += __shfl_down(v, o, 64);
    if (lane == 0) red[wid * NA + k] = v;
  }
  __syncthreads();
  if (threadIdx.x < NA) {
    float sm = 0.f;
#pragma unroll
    for (int w = 0; w < 8; ++w) sm += red[w * NA + threadIdx.x];
    covp[(size_t)nc * 192 + OFF + threadIdx.x] = sm;
  }
}

__global__ __launch_bounds__(512) void stage2_mom(
    const float* __restrict__ P, const float* __restrict__ L,
    float* __restrict__ covp) {
  __shared__ float red[8 * 81];
  int nc = blockIdx.x;
  const float* Pp = P + (size_t)nc * PP2A;
  const float* Lp = L + (size_t)nc * PP2A;
  if (blockIdx.y == 0)      mom_body<0>(Pp, Lp, covp, nc, red);
  else if (blockIdx.y == 1) mom_body<1>(Pp, Lp, covp, nc, red);
  else                      mom_body<2>(Pp, Lp, covp, nc, red);
}

// ---------------------------------------------------------------------------
// Stage 3: one 64-thread block per (n,c). Builds covariances in fp64 in LDS,
// Cholesky(la_cov+1e-5 I), triangular solve, Schur complement + 1e-6 I,
// Cholesky logdet. Result -> covp[nc*192 + 190..191] as double.
// ---------------------------------------------------------------------------
__global__ __launch_bounds__(64) void stage3_rmi(float* __restrict__ covp) {
  int nc  = blockIdx.x;
  int tid = threadIdx.x;
  const float* s = covp + (size_t)nc * 192;
  __shared__ double lc[81], pc[81], plc[81], mla[9], mpr[9];
  const double Minv = 1.0 / (double)MM;

  if (tid < 9)       mla[tid]     = (double)s[tid] * Minv;
  else if (tid < 18) mpr[tid - 9] = (double)s[tid] * Minv;
  __syncthreads();

  for (int e = tid; e < 81; e += 64) {
    int r = e / 9, c = e - 9 * (e / 9);
    int lo = r < c ? r : c, hi = r < c ? c : r;
    int k = lo * 9 - lo * (lo - 1) / 2 + (hi - lo);
    double a = (double)s[18 + k] * Minv - mla[r] * mla[c];
    if (r == c) a += 1e-5;
    lc[e] = a;
    pc[e] = (double)s[63 + k] * Minv - mpr[r] * mpr[c];
    plc[e] = (double)s[108 + e] * Minv - mpr[r] * mla[c];
  }
  __syncthreads();

  // Cholesky of lc (lower), column-by-column
  for (int j = 0; j < 9; ++j) {
    if (tid == 0) lc[j * 9 + j] = sqrt(lc[j * 9 + j]);
    __syncthreads();
    if (tid > j && tid < 9) lc[tid * 9 + j] /= lc[j * 9 + j];
    __syncthreads();
    if (tid > j && tid < 9) {
      double lij = lc[tid * 9 + j];
      for (int k = j + 1; k <= tid; ++k) lc[tid * 9 + k] -= lij * lc[k * 9 + j];
    }
    __syncthreads();
  }

  // Solve W * L1^T = plc (row d per lane), in place
  if (tid < 9) {
    int d = tid;
    for (int j = 0; j < 9; ++j) {
      double t = plc[d * 9 + j];
      for (int k = 0; k < j; ++k) t -= plc[d * 9 + k] * lc[j * 9 + k];
      plc[d * 9 + j] = t / lc[j * 9 + j];
    }
  }
  __syncthreads();

  // A = pc - W W^T + 1e-6 I (in place in pc)
  for (int e = tid; e < 81; e += 64) {
    int r = e / 9, c = e - 9 * (e / 9);
    double a = pc[e];
    for (int f = 0; f < 9; ++f) a -= plc[r * 9 + f] * plc[c * 9 + f];
    if (r == c) a += 1e-6;
    pc[e] = a;
  }
  __syncthreads();

  // Cholesky of pc
  for (int j = 0; j < 9; ++j) {
    if (tid == 0) pc[j * 9 + j] = sqrt(pc[j * 9 + j]);
    __syncthreads();
    if (tid > j && tid < 9) pc[tid * 9 + j] /= pc[j * 9 + j];
    __syncthreads();
    if (tid > j && tid < 9) {
      double lij = pc[tid * 9 + j];
      for (int k = j + 1; k <= tid; ++k) pc[tid * 9 + k] -= lij * pc[k * 9 + j];
    }
    __syncthreads();
  }

  if (tid == 0) {
    double sl = 0.0;
    for (int j = 0; j < 9; ++j) sl += log(pc[j * 9 + j] + 1e-8);
    *(double*)(covp + (size_t)nc * 192 + 190) = sl;  // rmi_{n,c}
  }
}

// ---------------------------------------------------------------------------
// Stage 4: reduce 76 fp64 partials -> out[0] = sum / (N * NUM_CLASSES)
// ---------------------------------------------------------------------------
__global__ __launch_bounds__(64) void stage4_reduce(
    const float* __restrict__ covp, float* __restrict__ out) {
  int tid = threadIdx.x;
  double v = 0.0;
  if (tid < NBATCH * NCLS)
    v = *(const double*)(covp + (size_t)tid * 192 + 190);
  if (tid + 64 < NBATCH * NCLS)
    v += *(const double*)(covp + (size_t)(tid + 64) * 192 + 190);
#pragma unroll
  for (int o = 32; o > 0; o >>= 1) v += __shfl_down(v, o, 64);
  if (tid == 0) out[0] = (float)(v / (double)(NBATCH * NCLS));
}

// ---------------------------------------------------------------------------
extern "C" void kernel_launch(void* const* d_in, const int* in_sizes, int n_in,
                              void* d_out, int out_size, void* d_ws, size_t ws_size,
                              hipStream_t stream) {
  const float* cls  = (const float*)d_in[0];
  const int* label  = (const int*)d_in[1];
  float* out = (float*)d_out;

  float* P    = (float*)d_ws;                              // 76*30096 f32
  float* L    = P + (size_t)NBATCH * NCLS * PP2A;          // 76*30096 f32
  float* covp = L + (size_t)NBATCH * NCLS * PP2A;          // 76*192 f32

  stage1_pool<<<NBATCH * PH, 512, 0, stream>>>(cls, label, P, L);
  dim3 g2(NBATCH * NCLS, 3, 1);
  stage2_mom<<<g2, 512, 0, stream>>>(P, L, covp);
  stage3_rmi<<<NBATCH * NCLS, 64, 0, stream>>>(covp);
  stage4_reduce<<<1, 64, 0, stream>>>(covp, out);
}